// Round 5
// baseline (467.664 us; speedup 1.0000x reference)
//
#include <hip/hip_runtime.h>

typedef unsigned short u16;
typedef unsigned int u32;
typedef float f32x4 __attribute__((ext_vector_type(4)));
typedef short s16x8 __attribute__((ext_vector_type(8)));

#define T_ 4
#define B_ 16
#define C_ 512
#define N_ 1024
#define YSZ 33554432  // 64*512*1024 (y output elements); attn follows in d_out

// ---- bf16 helpers (manual RNE) ----
__device__ __forceinline__ u16 f2bf(float f) {
  u32 u = __float_as_uint(f);
  u32 r = u + 0x7FFFu + ((u >> 16) & 1u);
  return (u16)(r >> 16);
}
__device__ __forceinline__ float bf2f(u16 h) { return __uint_as_float(((u32)h) << 16); }

// ---- async global->LDS, 16B per lane, wave-uniform LDS base ----
__device__ __forceinline__ void async16(const void* g, void* l) {
  __builtin_amdgcn_global_load_lds((const __attribute__((address_space(1))) void*)g,
                                   (__attribute__((address_space(3))) void*)l, 16, 0, 0);
}

// =====================================================================
// prep: split q_w/k_w into bf16 hi|lo concat [512][1024]; proj_w -> bf16;
//       BN constants (inv, bias) for q/k/p into consts[].
// =====================================================================
__global__ void prep_kernel(const float* __restrict__ qw, const float* __restrict__ kw,
                            const float* __restrict__ pw,
                            const float* __restrict__ qg, const float* __restrict__ qb,
                            const float* __restrict__ qm, const float* __restrict__ qv,
                            const float* __restrict__ kg, const float* __restrict__ kb,
                            const float* __restrict__ km, const float* __restrict__ kv,
                            const float* __restrict__ pg, const float* __restrict__ pbt,
                            const float* __restrict__ pm, const float* __restrict__ pv,
                            u16* __restrict__ whlq, u16* __restrict__ whlk,
                            u16* __restrict__ pwb, float* __restrict__ consts) {
  int blk = blockIdx.x, tid = threadIdx.x;
  if (blk < 512) {
    int d = blk;
    for (int c = tid; c < 512; c += 256) {
      float w = qw[d * 512 + c];
      u16 hi = f2bf(w);
      whlq[d * 1024 + c] = hi;
      whlq[d * 1024 + 512 + c] = f2bf(w - bf2f(hi));
      w = kw[d * 512 + c];
      hi = f2bf(w);
      whlk[d * 1024 + c] = hi;
      whlk[d * 1024 + 512 + c] = f2bf(w - bf2f(hi));
      pwb[d * 512 + c] = f2bf(pw[d * 512 + c]);
    }
  } else {
    for (int c = tid; c < 512; c += 256) {
      float inv = qg[c] / sqrtf(qv[c] + 1e-5f);
      consts[c] = inv; consts[512 + c] = qb[c] - qm[c] * inv;
      inv = kg[c] / sqrtf(kv[c] + 1e-5f);
      consts[1024 + c] = inv; consts[1536 + c] = kb[c] - km[c] * inv;
      inv = pg[c] / sqrtf(pv[c] + 1e-5f);
      consts[2048 + c] = inv; consts[2560 + c] = pbt[c] - pm[c] * inv;
    }
  }
}

// =====================================================================
// lif_x: x[t,b,c,n] f32 -> spikes xs[t,b,n,c] bf16 (LDS transpose).
// =====================================================================
__global__ __launch_bounds__(256) void lifx_kernel(const float* __restrict__ x,
                                                   u16* __restrict__ xs) {
  int b = blockIdx.z;
  int cbase = blockIdx.y * 64, nbase = blockIdx.x * 64;
  int tid = threadIdx.x;
  int c_l = tid >> 6, n_l = tid & 63;
  __shared__ __align__(16) u16 tile[64 * 72];
  float v[16];
#pragma unroll
  for (int i = 0; i < 16; ++i) v[i] = 0.f;
  for (int t = 0; t < 4; ++t) {
    const float* xp = x + ((size_t)(t * 16 + b) * 512 + cbase + c_l * 16) * 1024 + nbase + n_l;
#pragma unroll
    for (int i = 0; i < 16; ++i) {
      float xv = xp[(size_t)i * 1024];
      float vn = v[i] + 0.5f * (xv - v[i]);   // v + (x-v)/TAU, TAU=2 (bit-exact vs np)
      bool s = vn >= 1.0f;
      tile[n_l * 72 + c_l * 16 + i] = s ? 0x3F80 : 0;
      v[i] = s ? 0.f : vn;
    }
    __syncthreads();
    u16* yb = xs + ((size_t)(t * 16 + b) * 1024 + nbase) * 512 + cbase;
#pragma unroll
    for (int e = 0; e < 2; ++e) {
      int chunk = tid * 2 + e;
      int n = chunk >> 3, c0 = (chunk & 7) * 8;
      *(uint4*)&yb[(size_t)n * 512 + c0] = *(const uint4*)&tile[n * 72 + c0];
    }
    __syncthreads();
  }
}

// =====================================================================
// gemm_qk: MERGED conv_q + conv_k, 512 threads = 8 waves.
// Waves 0-3: q-tile (BN+LIF+head-sum+attn-LIF -> LDS + d_out).
// Waves 4-7: k-tile (BN+LIF, mask by attn from LDS, Ys transpose -> y).
// Single shared Bs stage serves both GEMMs: 80 KB/k-step for 512 MFMA
// (vs 96 KB for 2x256 in split kernels), barriers/t: 36 -> 19, and the
// attn q->k dependency stays on-chip.
// =====================================================================
__global__ __launch_bounds__(512, 2) void gemm_qk_kernel(
    const u16* __restrict__ Aq, const u16* __restrict__ Ak,
    const u16* __restrict__ Bbase, const float* __restrict__ consts,
    float* __restrict__ dout, u16* __restrict__ y) {
  const int tid = threadIdx.x;
  const int lane = tid & 63, w = tid >> 6;
  const bool isQ = w < 4;
  const int rw = isQ ? w : (w - 4);
  const int wm = rw >> 1, wn = rw & 1;
  const int quad = lane >> 4, l16 = lane & 15;
  const int b = blockIdx.z;
  const int m_blk = blockIdx.y * 128, n_blk = blockIdx.x * 128;
  const int srow = lane >> 3;
  const int scol = (((lane & 7) ^ srow) & 7) * 8;
  __shared__ __align__(16) u16 smem[40960];  // 80 KB: Aqh|Aql|Akh|Akl|Bs
  u16* Aqh = smem;
  u16* Aql = smem + 8192;
  u16* Akh = smem + 16384;
  u16* Akl = smem + 24576;
  u16* Bs  = smem + 32768;
  float* attn_s = (float*)(smem + 32768);  // aliases Bs (dead post-K-loop)
  u16* Ys = smem;                          // aliases A-stage region, stride 132
  u16* Ah = isQ ? Aqh : Akh;
  u16* Al = isQ ? Aql : Akl;
  const int cb = isQ ? 0 : 1024;  // consts base (q vs k BN)
  const int rxor = l16 & 7;
  float v[64];  // LIF state, [ti*4+tj]*4+r
#pragma unroll
  for (int i = 0; i < 64; ++i) v[i] = 0.f;
  float va[4] = {0.f, 0.f, 0.f, 0.f};  // attn LIF state (q-waves only)

  for (int t = 0; t < 4; ++t) {
    f32x4 acc[4][4];
    const f32x4 zero = {0.f, 0.f, 0.f, 0.f};
#pragma unroll
    for (int i = 0; i < 4; ++i)
#pragma unroll
      for (int j = 0; j < 4; ++j) acc[i][j] = zero;
    const u16* Bt = Bbase + (size_t)(t * 16 + b) * (N_ * C_);

    for (int k0 = 0; k0 < 512; k0 += 64) {
      // All 8 waves cooperatively stage all 5 buffers (2 issues each).
#pragma unroll
      for (int j = 0; j < 2; ++j) {
        int r = j * 64 + w * 8 + srow;
        int lo = (j * 64 + w * 8) * 64;
        const size_t ar = (size_t)(m_blk + r) * 1024 + k0 + scol;
        async16(Aq + ar,       &Aqh[lo]);
        async16(Aq + ar + 512, &Aql[lo]);
        async16(Ak + ar,       &Akh[lo]);
        async16(Ak + ar + 512, &Akl[lo]);
        async16(Bt + (size_t)(n_blk + r) * 512 + k0 + scol, &Bs[lo]);
      }
      __syncthreads();
#pragma unroll
      for (int kk = 0; kk < 2; ++kk) {
        s16x8 ah[4], al[4], bf[4];
        const int slot = ((kk * 4 + quad) ^ rxor) * 8;
#pragma unroll
        for (int ti = 0; ti < 4; ++ti) {
          ah[ti] = *(const s16x8*)&Ah[(wm * 64 + ti * 16 + l16) * 64 + slot];
          al[ti] = *(const s16x8*)&Al[(wm * 64 + ti * 16 + l16) * 64 + slot];
        }
#pragma unroll
        for (int tj = 0; tj < 4; ++tj)
          bf[tj] = *(const s16x8*)&Bs[(wn * 64 + tj * 16 + l16) * 64 + slot];
#pragma unroll
        for (int ti = 0; ti < 4; ++ti)
#pragma unroll
          for (int tj = 0; tj < 4; ++tj) {
            acc[ti][tj] = __builtin_amdgcn_mfma_f32_16x16x32_bf16(ah[ti], bf[tj], acc[ti][tj], 0, 0, 0);
            acc[ti][tj] = __builtin_amdgcn_mfma_f32_16x16x32_bf16(al[ti], bf[tj], acc[ti][tj], 0, 0, 0);
          }
      }
      __syncthreads();
    }

    // Phase 1: q-waves -> BN + LIF + head-sum + attn-LIF -> attn_s + d_out
    if (isQ) {
      float qp[4] = {0.f, 0.f, 0.f, 0.f};
#pragma unroll
      for (int ti = 0; ti < 4; ++ti) {
#pragma unroll
        for (int r = 0; r < 4; ++r) {
          int row = m_blk + wm * 64 + ti * 16 + quad * 4 + r;
          float iv = consts[row], ib = consts[512 + row];
#pragma unroll
          for (int tj = 0; tj < 4; ++tj) {
            float bnv = acc[ti][tj][r] * iv + ib;
            float vv = v[(ti * 4 + tj) * 4 + r];
            float vn = vv + 0.5f * (bnv - vv);
            bool s = vn >= 1.0f;
            v[(ti * 4 + tj) * 4 + r] = s ? 0.f : vn;
            qp[tj] += s ? 1.f : 0.f;
          }
        }
      }
      int h = (m_blk >> 6) + wm;
#pragma unroll
      for (int tj = 0; tj < 4; ++tj) {
        float q = qp[tj];
        q += __shfl_xor(q, 16, 64);
        q += __shfl_xor(q, 32, 64);  // full 64-channel head sum
        float vn = va[tj] + 0.5f * (q - va[tj]);  // exact dyadic
        bool s = vn >= 0.5f;
        va[tj] = s ? 0.f : vn;
        if (quad == 0) {
          int cl = wn * 64 + tj * 16 + l16;
          float sv = s ? 1.f : 0.f;
          attn_s[wm * 128 + cl] = sv;
          dout[(size_t)YSZ + ((size_t)(t * 16 + b) * 8 + h) * 1024 + n_blk + cl] = sv;
        }
      }
    }
    __syncthreads();  // attn_s visible; staging LDS free for Ys

    // Phase 2: k-waves -> BN + LIF + mask -> Ys transpose tile
    if (!isQ) {
      float at[4];
#pragma unroll
      for (int tj = 0; tj < 4; ++tj)
        at[tj] = attn_s[wm * 128 + wn * 64 + tj * 16 + l16];
#pragma unroll
      for (int ti = 0; ti < 4; ++ti) {
        u16 pk[4][4];
#pragma unroll
        for (int r = 0; r < 4; ++r) {
          int row = m_blk + wm * 64 + ti * 16 + quad * 4 + r;
          float iv = consts[cb + row], ib = consts[cb + 512 + row];
#pragma unroll
          for (int tj = 0; tj < 4; ++tj) {
            float bnv = acc[ti][tj][r] * iv + ib;
            float vv = v[(ti * 4 + tj) * 4 + r];
            float vn = vv + 0.5f * (bnv - vv);
            bool s = vn >= 1.0f;
            v[(ti * 4 + tj) * 4 + r] = s ? 0.f : vn;
            pk[tj][r] = (s && at[tj] != 0.f) ? 0x3F80 : 0;
          }
        }
#pragma unroll
        for (int tj = 0; tj < 4; ++tj) {
          int n_loc = wn * 64 + tj * 16 + l16;
          int c_loc = wm * 64 + ti * 16 + quad * 4;
          u32 lo2 = (u32)pk[tj][0] | ((u32)pk[tj][1] << 16);
          u32 hi2 = (u32)pk[tj][2] | ((u32)pk[tj][3] << 16);
          uint2 pv2; pv2.x = lo2; pv2.y = hi2;
          *(uint2*)&Ys[n_loc * 132 + c_loc] = pv2;
        }
      }
    }
    __syncthreads();  // Ys complete
    // coop store (all 8 waves): 128 rows x 128 u16, 256B/row coalesced
    u16* yb = y + ((size_t)(t * 16 + b) * 1024 + n_blk) * 512 + m_blk;
#pragma unroll
    for (int p = 0; p < 4; ++p) {
      int idx = p * 512 + tid;
      int rown = idx >> 4, ch = (idx & 15) * 8;
      *(uint4*)&yb[(size_t)rown * 512 + ch] = *(const uint4*)&Ys[rown * 132 + ch];
    }
    __syncthreads();  // Ys dead before next t's staging
  }
}

// =====================================================================
// gemm_proj: out[d,n] = (sum_k pw[d,k]*y[n,k] + proj_b)*p_inv + p_bias.
// =====================================================================
__global__ __launch_bounds__(256, 3) void gemm_proj_kernel(
    const u16* __restrict__ A, const u16* __restrict__ Bbase,
    float* __restrict__ outP, const float* __restrict__ projb,
    const float* __restrict__ consts) {
  const int tid = threadIdx.x;
  const int lane = tid & 63, w = tid >> 6;
  const int wm = w >> 1, wn = w & 1;
  const int quad = lane >> 4, l16 = lane & 15;
  const int tb = blockIdx.z;
  const int m_blk = blockIdx.y * 128, n_blk = blockIdx.x * 128;
  const int srow = lane >> 3;
  const int scol = (((lane & 7) ^ srow) & 7) * 8;
  __shared__ __align__(16) u16 As[128 * 64];
  __shared__ __align__(16) u16 Bs[128 * 64];
  f32x4 acc[4][4];
  const f32x4 zero = {0.f, 0.f, 0.f, 0.f};
#pragma unroll
  for (int i = 0; i < 4; ++i)
#pragma unroll
    for (int j = 0; j < 4; ++j) acc[i][j] = zero;
  const u16* Bt = Bbase + (size_t)tb * (N_ * C_);
  const int rxor = l16 & 7;

  for (int k0 = 0; k0 < 512; k0 += 64) {
#pragma unroll
    for (int i = 0; i < 4; ++i) {
      int r = i * 32 + w * 8 + srow;
      async16(A + (size_t)(m_blk + r) * 512 + k0 + scol, &As[(i * 32 + w * 8) * 64]);
      async16(Bt + (size_t)(n_blk + r) * 512 + k0 + scol, &Bs[(i * 32 + w * 8) * 64]);
    }
    __syncthreads();
#pragma unroll
    for (int kk = 0; kk < 2; ++kk) {
      s16x8 af[4], bf[4];
      const int slot = ((kk * 4 + quad) ^ rxor) * 8;
#pragma unroll
      for (int ti = 0; ti < 4; ++ti)
        af[ti] = *(const s16x8*)&As[(wm * 64 + ti * 16 + l16) * 64 + slot];
#pragma unroll
      for (int tj = 0; tj < 4; ++tj)
        bf[tj] = *(const s16x8*)&Bs[(wn * 64 + tj * 16 + l16) * 64 + slot];
#pragma unroll
      for (int ti = 0; ti < 4; ++ti)
#pragma unroll
        for (int tj = 0; tj < 4; ++tj)
          acc[ti][tj] = __builtin_amdgcn_mfma_f32_16x16x32_bf16(af[ti], bf[tj], acc[ti][tj], 0, 0, 0);
    }
    __syncthreads();
  }

  const float* pinv = consts + 2048;
  const float* pb2 = consts + 2560;
  float* o = outP + (size_t)tb * (C_ * N_);
#pragma unroll
  for (int ti = 0; ti < 4; ++ti) {
    int row0 = m_blk + wm * 64 + ti * 16 + quad * 4;
#pragma unroll
    for (int r = 0; r < 4; ++r) {
      int row = row0 + r;
      float bi = projb[row], piv = pinv[row], pbi = pb2[row];
#pragma unroll
      for (int tj = 0; tj < 4; ++tj) {
        int col = n_blk + wn * 64 + tj * 16 + l16;
        o[(size_t)row * N_ + col] = (acc[ti][tj][r] + bi) * piv + pbi;
      }
    }
  }
}

// =====================================================================
extern "C" void kernel_launch(void* const* d_in, const int* in_sizes, int n_in,
                              void* d_out, int out_size, void* d_ws, size_t ws_size,
                              hipStream_t stream) {
  const float* x   = (const float*)d_in[0];
  const float* qw  = (const float*)d_in[1];
  const float* qg  = (const float*)d_in[2];
  const float* qb  = (const float*)d_in[3];
  const float* qm  = (const float*)d_in[4];
  const float* qv  = (const float*)d_in[5];
  const float* kw  = (const float*)d_in[6];
  const float* kg  = (const float*)d_in[7];
  const float* kb  = (const float*)d_in[8];
  const float* km  = (const float*)d_in[9];
  const float* kv  = (const float*)d_in[10];
  const float* pw  = (const float*)d_in[11];
  const float* pb  = (const float*)d_in[12];
  const float* pg  = (const float*)d_in[13];
  const float* pbt = (const float*)d_in[14];
  const float* pm  = (const float*)d_in[15];
  const float* pv  = (const float*)d_in[16];
  float* out = (float*)d_out;
  char* ws = (char*)d_ws;

  u16* xs       = (u16*)ws;                    // 64 MB spikes [t,b,n,c]
  u16* y2       = (u16*)(ws + 67108864);       // 64 MB y [t,b,n,c]
  u16* whlq     = (u16*)(ws + 201326592);
  u16* whlk     = (u16*)(ws + 202375168);
  u16* pwb      = (u16*)(ws + 203423744);
  float* consts = (float*)(ws + 203948032);

  prep_kernel<<<513, 256, 0, stream>>>(qw, kw, pw, qg, qb, qm, qv, kg, kb, km, kv,
                                       pg, pbt, pm, pv, whlq, whlk, pwb, consts);
  lifx_kernel<<<dim3(16, 8, 16), 256, 0, stream>>>(x, xs);
  gemm_qk_kernel<<<dim3(8, 4, 16), 512, 0, stream>>>(whlq, whlk, xs, consts, out, y2);
  gemm_proj_kernel<<<dim3(8, 4, 64), 256, 0, stream>>>(pwb, y2, out, pb, consts);
}

// Round 6
// 452.934 us; speedup vs baseline: 1.0325x; 1.0325x over previous
//
#include <hip/hip_runtime.h>

typedef unsigned short u16;
typedef unsigned int u32;
typedef float f32x4 __attribute__((ext_vector_type(4)));
typedef short s16x8 __attribute__((ext_vector_type(8)));

#define T_ 4
#define B_ 16
#define C_ 512
#define N_ 1024
#define YSZ 33554432  // 64*512*1024 (y output elements); attn follows in d_out

// ---- bf16 helpers (manual RNE) ----
__device__ __forceinline__ u16 f2bf(float f) {
  u32 u = __float_as_uint(f);
  u32 r = u + 0x7FFFu + ((u >> 16) & 1u);
  return (u16)(r >> 16);
}
__device__ __forceinline__ float bf2f(u16 h) { return __uint_as_float(((u32)h) << 16); }

// ---- async global->LDS, 16B per lane, wave-uniform LDS base ----
__device__ __forceinline__ void async16(const void* g, void* l) {
  __builtin_amdgcn_global_load_lds((const __attribute__((address_space(1))) void*)g,
                                   (__attribute__((address_space(3))) void*)l, 16, 0, 0);
}

// =====================================================================
// prep: split q_w/k_w into bf16 hi|lo concat [512][1024]; proj_w -> bf16;
//       BN constants (inv, bias) for q/k/p into consts[].
// =====================================================================
__global__ void prep_kernel(const float* __restrict__ qw, const float* __restrict__ kw,
                            const float* __restrict__ pw,
                            const float* __restrict__ qg, const float* __restrict__ qb,
                            const float* __restrict__ qm, const float* __restrict__ qv,
                            const float* __restrict__ kg, const float* __restrict__ kb,
                            const float* __restrict__ km, const float* __restrict__ kv,
                            const float* __restrict__ pg, const float* __restrict__ pbt,
                            const float* __restrict__ pm, const float* __restrict__ pv,
                            u16* __restrict__ whlq, u16* __restrict__ whlk,
                            u16* __restrict__ pwb, float* __restrict__ consts) {
  int blk = blockIdx.x, tid = threadIdx.x;
  if (blk < 512) {
    int d = blk;
    for (int c = tid; c < 512; c += 256) {
      float w = qw[d * 512 + c];
      u16 hi = f2bf(w);
      whlq[d * 1024 + c] = hi;
      whlq[d * 1024 + 512 + c] = f2bf(w - bf2f(hi));
      w = kw[d * 512 + c];
      hi = f2bf(w);
      whlk[d * 1024 + c] = hi;
      whlk[d * 1024 + 512 + c] = f2bf(w - bf2f(hi));
      pwb[d * 512 + c] = f2bf(pw[d * 512 + c]);
    }
  } else {
    for (int c = tid; c < 512; c += 256) {
      float inv = qg[c] / sqrtf(qv[c] + 1e-5f);
      consts[c] = inv; consts[512 + c] = qb[c] - qm[c] * inv;
      inv = kg[c] / sqrtf(kv[c] + 1e-5f);
      consts[1024 + c] = inv; consts[1536 + c] = kb[c] - km[c] * inv;
      inv = pg[c] / sqrtf(pv[c] + 1e-5f);
      consts[2048 + c] = inv; consts[2560 + c] = pbt[c] - pm[c] * inv;
    }
  }
}

// =====================================================================
// lif_x: x[t,b,c,n] f32 -> spikes xs[t,b,n,c] bf16 (LDS transpose).
// =====================================================================
__global__ __launch_bounds__(256) void lifx_kernel(const float* __restrict__ x,
                                                   u16* __restrict__ xs) {
  int b = blockIdx.z;
  int cbase = blockIdx.y * 64, nbase = blockIdx.x * 64;
  int tid = threadIdx.x;
  int c_l = tid >> 6, n_l = tid & 63;
  __shared__ __align__(16) u16 tile[64 * 72];
  float v[16];
#pragma unroll
  for (int i = 0; i < 16; ++i) v[i] = 0.f;
  for (int t = 0; t < 4; ++t) {
    const float* xp = x + ((size_t)(t * 16 + b) * 512 + cbase + c_l * 16) * 1024 + nbase + n_l;
#pragma unroll
    for (int i = 0; i < 16; ++i) {
      float xv = xp[(size_t)i * 1024];
      float vn = v[i] + 0.5f * (xv - v[i]);   // v + (x-v)/TAU, TAU=2 (bit-exact vs np)
      bool s = vn >= 1.0f;
      tile[n_l * 72 + c_l * 16 + i] = s ? 0x3F80 : 0;
      v[i] = s ? 0.f : vn;
    }
    __syncthreads();
    u16* yb = xs + ((size_t)(t * 16 + b) * 1024 + nbase) * 512 + cbase;
#pragma unroll
    for (int e = 0; e < 2; ++e) {
      int chunk = tid * 2 + e;
      int n = chunk >> 3, c0 = (chunk & 7) * 8;
      *(uint4*)&yb[(size_t)n * 512 + c0] = *(const uint4*)&tile[n * 72 + c0];
    }
    __syncthreads();
  }
}

// =====================================================================
// gemm_qk: 1024 INDEPENDENT 256-thread blocks (z = b + 16*isK).
// q-blocks (isK=0): conv_q -> BN -> LIF -> head-sum -> attn-LIF -> d_out.
//   (q-spikes are never materialized.)
// k-blocks (isK=1): conv_k -> BN -> LIF -> UNMASKED spikes -> y2[t,b,n,c]
//   (attn mask deferred to proj's B-operand — removes the q->k dependency
//    so all 1024 blocks run concurrently: 3/CU resident + refill, block
//    phase drift hides the per-k-step vmcnt(0)+barrier drains.)
// K-loop: hi/lo interleave + XOR bank swizzle (R4-proven, conflicts=0).
// =====================================================================
__global__ __launch_bounds__(256, 2) void gemm_qk_kernel(
    const u16* __restrict__ Aq, const u16* __restrict__ Ak,
    const u16* __restrict__ Bbase, const float* __restrict__ consts,
    float* __restrict__ dout, u16* __restrict__ y) {
  const int tid = threadIdx.x;
  const int lane = tid & 63, w = tid >> 6;
  const int wm = w >> 1, wn = w & 1;
  const int quad = lane >> 4, l16 = lane & 15;
  const int z = blockIdx.z;
  const int b = z & 15;
  const bool isK = z >= 16;
  const int m_blk = blockIdx.y * 128, n_blk = blockIdx.x * 128;
  const int srow = lane >> 3;
  const int scol = (((lane & 7) ^ srow) & 7) * 8;
  __shared__ __align__(16) u16 smem[3 * 128 * 64];  // Ash | Asl | Bs ; Ys aliases
  u16* Ash = smem;
  u16* Asl = smem + 8192;
  u16* Bs  = smem + 16384;
  u16* Ys  = smem;  // stride 132, k-blocks only, dead/live disjoint from staging
  const u16* A = isK ? Ak : Aq;
  const int cb = isK ? 1024 : 0;
  const int rxor = l16 & 7;
  float v[64];  // LIF state, [ti*4+tj]*4+r
#pragma unroll
  for (int i = 0; i < 64; ++i) v[i] = 0.f;
  float va[4] = {0.f, 0.f, 0.f, 0.f};  // attn LIF state (q-blocks)

  for (int t = 0; t < 4; ++t) {
    f32x4 acc[4][4];
    const f32x4 zero = {0.f, 0.f, 0.f, 0.f};
#pragma unroll
    for (int i = 0; i < 4; ++i)
#pragma unroll
      for (int j = 0; j < 4; ++j) acc[i][j] = zero;
    const u16* Bt = Bbase + (size_t)(t * 16 + b) * (N_ * C_);

    for (int k0 = 0; k0 < 512; k0 += 64) {
#pragma unroll
      for (int i = 0; i < 4; ++i) {
        int r = i * 32 + w * 8 + srow;
        int lo = (i * 32 + w * 8) * 64;
        async16(A + (size_t)(m_blk + r) * 1024 + k0 + scol, &Ash[lo]);
        async16(A + (size_t)(m_blk + r) * 1024 + 512 + k0 + scol, &Asl[lo]);
        async16(Bt + (size_t)(n_blk + r) * 512 + k0 + scol, &Bs[lo]);
      }
      __syncthreads();
#pragma unroll
      for (int kk = 0; kk < 2; ++kk) {
        s16x8 ah[4], al[4], bf[4];
        const int slot = ((kk * 4 + quad) ^ rxor) * 8;
#pragma unroll
        for (int ti = 0; ti < 4; ++ti) {
          ah[ti] = *(const s16x8*)&Ash[(wm * 64 + ti * 16 + l16) * 64 + slot];
          al[ti] = *(const s16x8*)&Asl[(wm * 64 + ti * 16 + l16) * 64 + slot];
        }
#pragma unroll
        for (int tj = 0; tj < 4; ++tj)
          bf[tj] = *(const s16x8*)&Bs[(wn * 64 + tj * 16 + l16) * 64 + slot];
#pragma unroll
        for (int ti = 0; ti < 4; ++ti)
#pragma unroll
          for (int tj = 0; tj < 4; ++tj) {
            acc[ti][tj] = __builtin_amdgcn_mfma_f32_16x16x32_bf16(ah[ti], bf[tj], acc[ti][tj], 0, 0, 0);
            acc[ti][tj] = __builtin_amdgcn_mfma_f32_16x16x32_bf16(al[ti], bf[tj], acc[ti][tj], 0, 0, 0);
          }
      }
      __syncthreads();
    }

    if (!isK) {
      // q epilogue: BN + LIF + head-sum + attn-LIF -> d_out (attn only)
      float qp[4] = {0.f, 0.f, 0.f, 0.f};
#pragma unroll
      for (int ti = 0; ti < 4; ++ti) {
#pragma unroll
        for (int r = 0; r < 4; ++r) {
          int row = m_blk + wm * 64 + ti * 16 + quad * 4 + r;
          float iv = consts[row], ib = consts[512 + row];
#pragma unroll
          for (int tj = 0; tj < 4; ++tj) {
            float bnv = acc[ti][tj][r] * iv + ib;
            float vv = v[(ti * 4 + tj) * 4 + r];
            float vn = vv + 0.5f * (bnv - vv);
            bool s = vn >= 1.0f;
            v[(ti * 4 + tj) * 4 + r] = s ? 0.f : vn;
            qp[tj] += s ? 1.f : 0.f;
          }
        }
      }
      int h = (m_blk >> 6) + wm;
#pragma unroll
      for (int tj = 0; tj < 4; ++tj) {
        float q = qp[tj];
        q += __shfl_xor(q, 16, 64);
        q += __shfl_xor(q, 32, 64);  // full 64-channel head sum
        float vn = va[tj] + 0.5f * (q - va[tj]);  // exact dyadic
        bool s = vn >= 0.5f;
        va[tj] = s ? 0.f : vn;
        if (quad == 0) {
          int col = n_blk + wn * 64 + tj * 16 + l16;
          dout[(size_t)YSZ + ((size_t)(t * 16 + b) * 8 + h) * 1024 + col] = s ? 1.f : 0.f;
        }
      }
    } else {
      // k epilogue: BN + LIF -> UNMASKED spikes -> Ys transpose -> y2
#pragma unroll
      for (int ti = 0; ti < 4; ++ti) {
        u16 pk[4][4];
#pragma unroll
        for (int r = 0; r < 4; ++r) {
          int row = m_blk + wm * 64 + ti * 16 + quad * 4 + r;
          float iv = consts[cb + row], ib = consts[cb + 512 + row];
#pragma unroll
          for (int tj = 0; tj < 4; ++tj) {
            float bnv = acc[ti][tj][r] * iv + ib;
            float vv = v[(ti * 4 + tj) * 4 + r];
            float vn = vv + 0.5f * (bnv - vv);
            bool s = vn >= 1.0f;
            v[(ti * 4 + tj) * 4 + r] = s ? 0.f : vn;
            pk[tj][r] = s ? 0x3F80 : 0;
          }
        }
#pragma unroll
        for (int tj = 0; tj < 4; ++tj) {
          int n_loc = wn * 64 + tj * 16 + l16;
          int c_loc = wm * 64 + ti * 16 + quad * 4;
          u32 lo2 = (u32)pk[tj][0] | ((u32)pk[tj][1] << 16);
          u32 hi2 = (u32)pk[tj][2] | ((u32)pk[tj][3] << 16);
          uint2 pv2; pv2.x = lo2; pv2.y = hi2;
          *(uint2*)&Ys[n_loc * 132 + c_loc] = pv2;
        }
      }
      __syncthreads();
      u16* yb = y + ((size_t)(t * 16 + b) * 1024 + n_blk) * 512 + m_blk;
#pragma unroll
      for (int p = 0; p < 8; ++p) {
        int idx = p * 256 + tid;
        int rown = idx >> 4, ch = (idx & 15) * 8;
        *(uint4*)&yb[(size_t)rown * 512 + ch] = *(const uint4*)&Ys[rown * 132 + ch];
      }
      __syncthreads();  // Ys dead before next t's staging
    }
  }
}

// =====================================================================
// gemm_proj: out[d,n] = (sum_k pw[d,k]*ks[n,k]*attn[h(k),n] + proj_b)*p_inv
//            + p_bias.  The attn mask is applied to the B fragments: each
//            64-channel k-chunk is exactly one head, so the mask is a
//            per-lane scalar (n) uniform over the fragment — exact 0/1.
// =====================================================================
__global__ __launch_bounds__(256, 3) void gemm_proj_kernel(
    const u16* __restrict__ A, const u16* __restrict__ Bbase,
    float* __restrict__ outP, const float* __restrict__ projb,
    const float* __restrict__ consts, const float* __restrict__ attn) {
  const int tid = threadIdx.x;
  const int lane = tid & 63, w = tid >> 6;
  const int wm = w >> 1, wn = w & 1;
  const int quad = lane >> 4, l16 = lane & 15;
  const int tb = blockIdx.z;
  const int m_blk = blockIdx.y * 128, n_blk = blockIdx.x * 128;
  const int srow = lane >> 3;
  const int scol = (((lane & 7) ^ srow) & 7) * 8;
  __shared__ __align__(16) u16 As[128 * 64];
  __shared__ __align__(16) u16 Bs[128 * 64];
  f32x4 acc[4][4];
  const f32x4 zero = {0.f, 0.f, 0.f, 0.f};
  const s16x8 zero8 = {0, 0, 0, 0, 0, 0, 0, 0};
#pragma unroll
  for (int i = 0; i < 4; ++i)
#pragma unroll
    for (int j = 0; j < 4; ++j) acc[i][j] = zero;
  const u16* Bt = Bbase + (size_t)tb * (N_ * C_);
  const float* attn_tb = attn + (size_t)tb * 8192;
  const int rxor = l16 & 7;

  for (int k0 = 0; k0 < 512; k0 += 64) {
#pragma unroll
    for (int i = 0; i < 4; ++i) {
      int r = i * 32 + w * 8 + srow;
      async16(A + (size_t)(m_blk + r) * 512 + k0 + scol, &As[(i * 32 + w * 8) * 64]);
      async16(Bt + (size_t)(n_blk + r) * 512 + k0 + scol, &Bs[(i * 32 + w * 8) * 64]);
    }
    // attn mask for this k-chunk's head (issued early, L2-hot)
    const int h = k0 >> 6;
    float atf[4];
#pragma unroll
    for (int tj = 0; tj < 4; ++tj)
      atf[tj] = attn_tb[h * 1024 + n_blk + wn * 64 + tj * 16 + l16];
    __syncthreads();
#pragma unroll
    for (int kk = 0; kk < 2; ++kk) {
      s16x8 af[4], bf[4];
      const int slot = ((kk * 4 + quad) ^ rxor) * 8;
#pragma unroll
      for (int ti = 0; ti < 4; ++ti)
        af[ti] = *(const s16x8*)&As[(wm * 64 + ti * 16 + l16) * 64 + slot];
#pragma unroll
      for (int tj = 0; tj < 4; ++tj) {
        bf[tj] = *(const s16x8*)&Bs[(wn * 64 + tj * 16 + l16) * 64 + slot];
        bf[tj] = (atf[tj] != 0.f) ? bf[tj] : zero8;  // exact 0/1 mask
      }
#pragma unroll
      for (int ti = 0; ti < 4; ++ti)
#pragma unroll
        for (int tj = 0; tj < 4; ++tj)
          acc[ti][tj] = __builtin_amdgcn_mfma_f32_16x16x32_bf16(af[ti], bf[tj], acc[ti][tj], 0, 0, 0);
    }
    __syncthreads();
  }

  const float* pinv = consts + 2048;
  const float* pb2 = consts + 2560;
  float* o = outP + (size_t)tb * (C_ * N_);
#pragma unroll
  for (int ti = 0; ti < 4; ++ti) {
    int row0 = m_blk + wm * 64 + ti * 16 + quad * 4;
#pragma unroll
    for (int r = 0; r < 4; ++r) {
      int row = row0 + r;
      float bi = projb[row], piv = pinv[row], pbi = pb2[row];
#pragma unroll
      for (int tj = 0; tj < 4; ++tj) {
        int col = n_blk + wn * 64 + tj * 16 + l16;
        o[(size_t)row * N_ + col] = (acc[ti][tj][r] + bi) * piv + pbi;
      }
    }
  }
}

// =====================================================================
extern "C" void kernel_launch(void* const* d_in, const int* in_sizes, int n_in,
                              void* d_out, int out_size, void* d_ws, size_t ws_size,
                              hipStream_t stream) {
  const float* x   = (const float*)d_in[0];
  const float* qw  = (const float*)d_in[1];
  const float* qg  = (const float*)d_in[2];
  const float* qb  = (const float*)d_in[3];
  const float* qm  = (const float*)d_in[4];
  const float* qv  = (const float*)d_in[5];
  const float* kw  = (const float*)d_in[6];
  const float* kg  = (const float*)d_in[7];
  const float* kb  = (const float*)d_in[8];
  const float* km  = (const float*)d_in[9];
  const float* kv  = (const float*)d_in[10];
  const float* pw  = (const float*)d_in[11];
  const float* pb  = (const float*)d_in[12];
  const float* pg  = (const float*)d_in[13];
  const float* pbt = (const float*)d_in[14];
  const float* pm  = (const float*)d_in[15];
  const float* pv  = (const float*)d_in[16];
  float* out = (float*)d_out;
  char* ws = (char*)d_ws;

  u16* xs       = (u16*)ws;                    // 64 MB spikes [t,b,n,c]
  u16* y2       = (u16*)(ws + 67108864);       // 64 MB k-spikes [t,b,n,c]
  u16* whlq     = (u16*)(ws + 201326592);
  u16* whlk     = (u16*)(ws + 202375168);
  u16* pwb      = (u16*)(ws + 203423744);
  float* consts = (float*)(ws + 203948032);

  prep_kernel<<<513, 256, 0, stream>>>(qw, kw, pw, qg, qb, qm, qv, kg, kb, km, kv,
                                       pg, pbt, pm, pv, whlq, whlk, pwb, consts);
  lifx_kernel<<<dim3(16, 8, 16), 256, 0, stream>>>(x, xs);
  gemm_qk_kernel<<<dim3(8, 4, 32), 256, 0, stream>>>(whlq, whlk, xs, consts, out, y2);
  gemm_proj_kernel<<<dim3(8, 4, 64), 256, 0, stream>>>(pwb, y2, out, pb, consts,
                                                       out + YSZ);
}